// Round 1
// baseline (82.566 us; speedup 1.0000x reference)
//
#include <hip/hip_runtime.h>
#include <math.h>

#define HW 4096      // 64*64
#define CS 32        // channels per branch
#define NS 128       // B*GROUPS samples
#define NPLANES 8192 // NS * 64

__device__ __forceinline__ float sigmoidf_(float x) {
    return 1.0f / (1.0f + __expf(-x));
}

// ---------------- K1: per-plane sum & sumsq over 4096 elems ----------------
__global__ __launch_bounds__(256) void stats_kernel(const float* __restrict__ x,
                                                    float* __restrict__ sums,
                                                    float* __restrict__ sumsq) {
    const int P = blockIdx.x;
    const int tid = threadIdx.x;
    const float4* p4 = (const float4*)(x + (size_t)P * HW);
    float s = 0.f, s2 = 0.f;
#pragma unroll
    for (int k = 0; k < 4; ++k) {
        float4 v = p4[tid + k * 256];
        s  += v.x + v.y + v.z + v.w;
        s2 += v.x * v.x + v.y * v.y + v.z * v.z + v.w * v.w;
    }
    for (int off = 32; off > 0; off >>= 1) {
        s  += __shfl_down(s, off, 64);
        s2 += __shfl_down(s2, off, 64);
    }
    __shared__ float ls[4], ls2[4];
    const int wave = tid >> 6, lane = tid & 63;
    if (lane == 0) { ls[wave] = s; ls2[wave] = s2; }
    __syncthreads();
    if (tid == 0) {
        sums[P]  = ls[0] + ls[1] + ls[2] + ls[3];
        sumsq[P] = ls2[0] + ls2[1] + ls2[2] + ls2[3];
    }
}

// ---------------- K2: branch0 gates (incl. distill MLP) + branch1 IN stats ----------------
__global__ __launch_bounds__(64) void gates0_kernel(
    const float* __restrict__ sums, const float* __restrict__ sumsq,
    const float* __restrict__ cw, const float* __restrict__ cb,
    const float* __restrict__ fc1w, const float* __restrict__ fc1b,
    const float* __restrict__ lnw, const float* __restrict__ lnb,
    const float* __restrict__ fc2w, const float* __restrict__ fc2b,
    float* __restrict__ s0, float* __restrict__ mu1, float* __restrict__ rs1) {
    const int n = blockIdx.x;
    const int tid = threadIdx.x;
    __shared__ float p[CS], q[CS], r[CS];
    float g0 = 0.f, qv = 0.f;
    const int c = tid;
    if (tid < CS) {
        float mean = sums[n * 64 + c] * (1.0f / HW);
        g0 = sigmoidf_(cw[c] * mean + cb[c]);
        p[c] = mean * (1.0f - g0);   // mean of x_reid_0
    } else {
        int cc = tid - CS;
        float mean = sums[n * 64 + CS + cc] * (1.0f / HW);
        float m2   = sumsq[n * 64 + CS + cc] * (1.0f / HW);
        float var  = m2 - mean * mean;
        mu1[n * CS + cc] = mean;
        rs1[n * CS + cc] = rsqrtf(var + 1e-5f);
    }
    __syncthreads();
    if (tid < CS) {
        qv = fc1b[c];
        for (int j = 0; j < CS; ++j) qv += fc1w[c * CS + j] * p[j];
        q[c] = qv;
    }
    __syncthreads();
    if (tid < CS) {
        float mu = 0.f;
        for (int j = 0; j < CS; ++j) mu += q[j];
        mu *= (1.0f / CS);
        float var = 0.f;
        for (int j = 0; j < CS; ++j) { float d = q[j] - mu; var += d * d; }
        var *= (1.0f / CS);
        float qn = (qv - mu) * rsqrtf(var + 1e-5f) * lnw[c] + lnb[c];
        r[c] = fmaxf(qn, 0.f);
    }
    __syncthreads();
    if (tid < CS) {
        float sv = fc2b[c];
        for (int j = 0; j < CS; ++j) sv += fc2w[c * CS + j] * r[j];
        float gd = sigmoidf_(sv);
        s0[n * CS + c] = g0 + (1.0f - g0) * gd;
    }
}

// ---------------- K3: branch0 output (scalar scale) + branch1 sum(xs) ----------------
__global__ __launch_bounds__(256) void mid_kernel(
    const float* __restrict__ x, float* __restrict__ out,
    const float* __restrict__ s0,
    const float* __restrict__ mu1, const float* __restrict__ rs1,
    const float* __restrict__ gnw, const float* __restrict__ gnb,
    const float* __restrict__ sw, const float* __restrict__ sb,
    float* __restrict__ sumxs) {
    const int P = blockIdx.x;
    const int n = P >> 6, cc = P & 63;
    const int tid = threadIdx.x;
    const float4* xp = (const float4*)(x + (size_t)P * HW);
    __shared__ float ls[4];
    if (cc < CS) {
        const float scale = s0[n * CS + cc];
        float4* op = (float4*)(out + (size_t)P * HW);
#pragma unroll
        for (int k = 0; k < 4; ++k) {
            float4 v = xp[tid + k * 256];
            v.x *= scale; v.y *= scale; v.z *= scale; v.w *= scale;
            op[tid + k * 256] = v;
        }
    } else {
        const int c = cc - CS;
        const float mu = mu1[n * CS + c], rs = rs1[n * CS + c];
        const float a  = gnw[c] * rs;
        const float b0 = gnb[c] - mu * a;  // gn: x*a + b0
        const float sbv = sb[c];
        const float4* wp = (const float4*)(sw + (size_t)c * HW);
        float s = 0.f;
#pragma unroll
        for (int k = 0; k < 4; ++k) {
            float4 v = xp[tid + k * 256];
            float4 w = wp[tid + k * 256];
            s += v.x * sigmoidf_(w.x * (v.x * a + b0) + sbv);
            s += v.y * sigmoidf_(w.y * (v.y * a + b0) + sbv);
            s += v.z * sigmoidf_(w.z * (v.z * a + b0) + sbv);
            s += v.w * sigmoidf_(w.w * (v.w * a + b0) + sbv);
        }
        for (int off = 32; off > 0; off >>= 1) s += __shfl_down(s, off, 64);
        const int wave = tid >> 6, lane = tid & 63;
        if (lane == 0) ls[wave] = s;
        __syncthreads();
        if (tid == 0) sumxs[n * CS + c] = ls[0] + ls[1] + ls[2] + ls[3];
    }
}

// ---------------- K4: branch1 distill gates ----------------
__global__ __launch_bounds__(64) void gates1_kernel(
    const float* __restrict__ mu1, const float* __restrict__ sumxs,
    const float* __restrict__ fc1w, const float* __restrict__ fc1b,
    const float* __restrict__ lnw, const float* __restrict__ lnb,
    const float* __restrict__ fc2w, const float* __restrict__ fc2b,
    float* __restrict__ gd1) {
    const int n = blockIdx.x;
    const int tid = threadIdx.x;
    __shared__ float p[CS], q[CS], r[CS];
    float qv = 0.f;
    const int c = tid;
    if (tid < CS) {
        p[c] = mu1[n * CS + c] - sumxs[n * CS + c] * (1.0f / HW); // mean of x_reid_1
    }
    __syncthreads();
    if (tid < CS) {
        qv = fc1b[c];
        for (int j = 0; j < CS; ++j) qv += fc1w[c * CS + j] * p[j];
        q[c] = qv;
    }
    __syncthreads();
    if (tid < CS) {
        float mu = 0.f;
        for (int j = 0; j < CS; ++j) mu += q[j];
        mu *= (1.0f / CS);
        float var = 0.f;
        for (int j = 0; j < CS; ++j) { float d = q[j] - mu; var += d * d; }
        var *= (1.0f / CS);
        float qn = (qv - mu) * rsqrtf(var + 1e-5f) * lnw[c] + lnb[c];
        r[c] = fmaxf(qn, 0.f);
    }
    __syncthreads();
    if (tid < CS) {
        float sv = fc2b[c];
        for (int j = 0; j < CS; ++j) sv += fc2w[c * CS + j] * r[j];
        gd1[n * CS + c] = sigmoidf_(sv);
    }
}

// ---------------- K5: branch1 output (recompute xs, blend with gd1) ----------------
__global__ __launch_bounds__(256) void out1_kernel(
    const float* __restrict__ x, float* __restrict__ out,
    const float* __restrict__ mu1, const float* __restrict__ rs1,
    const float* __restrict__ gnw, const float* __restrict__ gnb,
    const float* __restrict__ sw, const float* __restrict__ sb,
    const float* __restrict__ gd1) {
    const int nb = blockIdx.x;
    const int n = nb >> 5, c = nb & 31;
    const int tid = threadIdx.x;
    const size_t off = ((size_t)n * 64 + CS + c) * HW;
    const float4* xp = (const float4*)(x + off);
    float4* op = (float4*)(out + off);
    const float g = gd1[n * CS + c];
    const float mu = mu1[n * CS + c], rs = rs1[n * CS + c];
    const float a  = gnw[c] * rs;
    const float b0 = gnb[c] - mu * a;
    const float sbv = sb[c];
    const float4* wp = (const float4*)(sw + (size_t)c * HW);
#pragma unroll
    for (int k = 0; k < 4; ++k) {
        float4 v = xp[tid + k * 256];
        float4 w = wp[tid + k * 256];
        float4 o;
        float sg;
        sg = sigmoidf_(w.x * (v.x * a + b0) + sbv); o.x = v.x * (sg + (1.f - sg) * g);
        sg = sigmoidf_(w.y * (v.y * a + b0) + sbv); o.y = v.y * (sg + (1.f - sg) * g);
        sg = sigmoidf_(w.z * (v.z * a + b0) + sbv); o.z = v.z * (sg + (1.f - sg) * g);
        sg = sigmoidf_(w.w * (v.w * a + b0) + sbv); o.w = v.w * (sg + (1.f - sg) * g);
        op[tid + k * 256] = o;
    }
}

extern "C" void kernel_launch(void* const* d_in, const int* in_sizes, int n_in,
                              void* d_out, int out_size, void* d_ws, size_t ws_size,
                              hipStream_t stream) {
    const float* x    = (const float*)d_in[0];
    const float* cw   = (const float*)d_in[1];
    const float* cb   = (const float*)d_in[2];
    const float* sw   = (const float*)d_in[3];
    const float* sb   = (const float*)d_in[4];
    const float* gnw  = (const float*)d_in[5];
    const float* gnb  = (const float*)d_in[6];
    const float* fc1w = (const float*)d_in[7];
    const float* fc1b = (const float*)d_in[8];
    const float* lnw  = (const float*)d_in[9];
    const float* lnb  = (const float*)d_in[10];
    const float* fc2w = (const float*)d_in[11];
    const float* fc2b = (const float*)d_in[12];
    float* out = (float*)d_out;
    float* ws  = (float*)d_ws;

    float* sums  = ws;             // 8192
    float* sumsq = ws + 8192;      // 8192
    float* s0    = ws + 16384;     // 4096
    float* mu1   = ws + 20480;     // 4096
    float* rs1   = ws + 24576;     // 4096
    float* sumxs = ws + 28672;     // 4096
    float* gd1   = ws + 32768;     // 4096

    stats_kernel<<<NPLANES, 256, 0, stream>>>(x, sums, sumsq);
    gates0_kernel<<<NS, 64, 0, stream>>>(sums, sumsq, cw, cb, fc1w, fc1b,
                                         lnw, lnb, fc2w, fc2b, s0, mu1, rs1);
    mid_kernel<<<NPLANES, 256, 0, stream>>>(x, out, s0, mu1, rs1, gnw, gnb, sw, sb, sumxs);
    gates1_kernel<<<NS, 64, 0, stream>>>(mu1, sumxs, fc1w, fc1b, lnw, lnb,
                                         fc2w, fc2b, gd1);
    out1_kernel<<<NPLANES / 2, 256, 0, stream>>>(x, out, mu1, rs1, gnw, gnb, sw, sb, gd1);
}

// Round 2
// 69.185 us; speedup vs baseline: 1.1934x; 1.1934x over previous
//
#include <hip/hip_runtime.h>
#include <math.h>

#define HW 4096      // 64*64
#define CS 32        // channels per branch
#define NS 128       // B*GROUPS samples
#define NPLANES 8192 // NS * 64
#define EPS 1e-5f

__device__ __forceinline__ float sigmoidf_(float x) {
    return 1.0f / (1.0f + __expf(-x));
}

// block-wide (256 thr, 4 waves) sum reduce; result valid in thread 0
__device__ __forceinline__ float block_reduce(float s, float* ls, int tid) {
    for (int off = 32; off > 0; off >>= 1) s += __shfl_down(s, off, 64);
    const int wave = tid >> 6, lane = tid & 63;
    if (lane == 0) ls[wave] = s;
    __syncthreads();
    return ls[0] + ls[1] + ls[2] + ls[3];
}

// ---------------- K1: one read of x.
// branch0 plane -> channel sum; branch1 plane -> mu, rs, sum(xs) (reg-staged)
__global__ __launch_bounds__(256) void pass1_kernel(
    const float* __restrict__ x,
    const float* __restrict__ gnw, const float* __restrict__ gnb,
    const float* __restrict__ sw,  const float* __restrict__ sb,
    float* __restrict__ sums0, float* __restrict__ mu1,
    float* __restrict__ rs1,   float* __restrict__ sumxs) {
    const int P = blockIdx.x;
    const int n = P >> 6, cc = P & 63;
    const int tid = threadIdx.x;
    const float4* xp = (const float4*)(x + (size_t)P * HW);
    __shared__ float ls[4];
    __shared__ float bc[2];

    if (cc < CS) {
        // branch0: only need the plane sum
        float s = 0.f;
#pragma unroll
        for (int k = 0; k < 4; ++k) {
            float4 v = xp[tid + k * 256];
            s += v.x + v.y + v.z + v.w;
        }
        s = block_reduce(s, ls, tid);
        if (tid == 0) sums0[n * CS + cc] = s;
    } else {
        const int c = cc - CS;
        // stage 16 elements in registers
        float4 v[4];
        float s = 0.f, s2 = 0.f;
#pragma unroll
        for (int k = 0; k < 4; ++k) {
            v[k] = xp[tid + k * 256];
            s  += v[k].x + v[k].y + v[k].z + v[k].w;
            s2 += v[k].x * v[k].x + v[k].y * v[k].y
                + v[k].z * v[k].z + v[k].w * v[k].w;
        }
        for (int off = 32; off > 0; off >>= 1) {
            s  += __shfl_down(s, off, 64);
            s2 += __shfl_down(s2, off, 64);
        }
        __shared__ float ls2[4];
        const int wave = tid >> 6, lane = tid & 63;
        if (lane == 0) { ls[wave] = s; ls2[wave] = s2; }
        __syncthreads();
        if (tid == 0) {
            float st  = ls[0] + ls[1] + ls[2] + ls[3];
            float s2t = ls2[0] + ls2[1] + ls2[2] + ls2[3];
            float mu  = st * (1.0f / HW);
            float var = s2t * (1.0f / HW) - mu * mu;
            float rs  = rsqrtf(var + EPS);
            mu1[n * CS + c] = mu;
            rs1[n * CS + c] = rs;
            bc[0] = mu; bc[1] = rs;
        }
        __syncthreads();
        const float mu = bc[0], rs = bc[1];
        const float a  = gnw[c] * rs;
        const float b0 = gnb[c] - mu * a;
        const float sbv = sb[c];
        const float4* wp = (const float4*)(sw + (size_t)c * HW);
        float sx = 0.f;
#pragma unroll
        for (int k = 0; k < 4; ++k) {
            float4 w = wp[tid + k * 256];
            sx += v[k].x * sigmoidf_(w.x * (v[k].x * a + b0) + sbv);
            sx += v[k].y * sigmoidf_(w.y * (v[k].y * a + b0) + sbv);
            sx += v[k].z * sigmoidf_(w.z * (v[k].z * a + b0) + sbv);
            sx += v[k].w * sigmoidf_(w.w * (v[k].w * a + b0) + sbv);
        }
        __syncthreads();   // ls reuse
        sx = block_reduce(sx, ls, tid);
        if (tid == 0) sumxs[n * CS + c] = sx;
    }
}

// ---------------- K2: both distill-gate MLPs (threads 0-31: branch0, 32-63: branch1)
__global__ __launch_bounds__(64) void gates_kernel(
    const float* __restrict__ sums0,
    const float* __restrict__ mu1, const float* __restrict__ sumxs,
    const float* __restrict__ cw,  const float* __restrict__ cb,
    const float* __restrict__ fc1w, const float* __restrict__ fc1b,
    const float* __restrict__ lnw, const float* __restrict__ lnb,
    const float* __restrict__ fc2w, const float* __restrict__ fc2b,
    float* __restrict__ s0, float* __restrict__ gd1) {
    const int n = blockIdx.x;
    const int tid = threadIdx.x;
    const int half = tid >> 5, c = tid & 31;
    __shared__ float p[2][CS], q[2][CS], r[2][CS];
    float g0 = 0.f;
    if (half == 0) {
        float mean = sums0[n * CS + c] * (1.0f / HW);
        g0 = sigmoidf_(cw[c] * mean + cb[c]);
        p[0][c] = mean * (1.0f - g0);               // mean of x_reid_0
    } else {
        p[1][c] = mu1[n * CS + c] - sumxs[n * CS + c] * (1.0f / HW); // mean of x_reid_1
    }
    __syncthreads();
    float qv = fc1b[c];
    for (int j = 0; j < CS; ++j) qv += fc1w[c * CS + j] * p[half][j];
    q[half][c] = qv;
    __syncthreads();
    float mu = 0.f;
    for (int j = 0; j < CS; ++j) mu += q[half][j];
    mu *= (1.0f / CS);
    float var = 0.f;
    for (int j = 0; j < CS; ++j) { float d = q[half][j] - mu; var += d * d; }
    var *= (1.0f / CS);
    float qn = (qv - mu) * rsqrtf(var + EPS) * lnw[c] + lnb[c];
    r[half][c] = fmaxf(qn, 0.f);
    __syncthreads();
    float sv = fc2b[c];
    for (int j = 0; j < CS; ++j) sv += fc2w[c * CS + j] * r[half][j];
    float gd = sigmoidf_(sv);
    if (half == 0) s0[n * CS + c] = g0 + (1.0f - g0) * gd;
    else           gd1[n * CS + c] = gd;
}

// ---------------- K3: output pass (both branches)
__global__ __launch_bounds__(256) void out_kernel(
    const float* __restrict__ x, float* __restrict__ out,
    const float* __restrict__ s0,
    const float* __restrict__ mu1, const float* __restrict__ rs1,
    const float* __restrict__ gnw, const float* __restrict__ gnb,
    const float* __restrict__ sw,  const float* __restrict__ sb,
    const float* __restrict__ gd1) {
    const int P = blockIdx.x;
    const int n = P >> 6, cc = P & 63;
    const int tid = threadIdx.x;
    const float4* xp = (const float4*)(x + (size_t)P * HW);
    float4* op = (float4*)(out + (size_t)P * HW);
    if (cc < CS) {
        const float scale = s0[n * CS + cc];
#pragma unroll
        for (int k = 0; k < 4; ++k) {
            float4 v = xp[tid + k * 256];
            v.x *= scale; v.y *= scale; v.z *= scale; v.w *= scale;
            op[tid + k * 256] = v;
        }
    } else {
        const int c = cc - CS;
        const float g  = gd1[n * CS + c];
        const float mu = mu1[n * CS + c], rs = rs1[n * CS + c];
        const float a  = gnw[c] * rs;
        const float b0 = gnb[c] - mu * a;
        const float sbv = sb[c];
        const float4* wp = (const float4*)(sw + (size_t)c * HW);
#pragma unroll
        for (int k = 0; k < 4; ++k) {
            float4 v = xp[tid + k * 256];
            float4 w = wp[tid + k * 256];
            float4 o; float sg;
            sg = sigmoidf_(w.x * (v.x * a + b0) + sbv); o.x = v.x * (sg + (1.f - sg) * g);
            sg = sigmoidf_(w.y * (v.y * a + b0) + sbv); o.y = v.y * (sg + (1.f - sg) * g);
            sg = sigmoidf_(w.z * (v.z * a + b0) + sbv); o.z = v.z * (sg + (1.f - sg) * g);
            sg = sigmoidf_(w.w * (v.w * a + b0) + sbv); o.w = v.w * (sg + (1.f - sg) * g);
            op[tid + k * 256] = o;
        }
    }
}

extern "C" void kernel_launch(void* const* d_in, const int* in_sizes, int n_in,
                              void* d_out, int out_size, void* d_ws, size_t ws_size,
                              hipStream_t stream) {
    const float* x    = (const float*)d_in[0];
    const float* cw   = (const float*)d_in[1];
    const float* cb   = (const float*)d_in[2];
    const float* sw   = (const float*)d_in[3];
    const float* sb   = (const float*)d_in[4];
    const float* gnw  = (const float*)d_in[5];
    const float* gnb  = (const float*)d_in[6];
    const float* fc1w = (const float*)d_in[7];
    const float* fc1b = (const float*)d_in[8];
    const float* lnw  = (const float*)d_in[9];
    const float* lnb  = (const float*)d_in[10];
    const float* fc2w = (const float*)d_in[11];
    const float* fc2b = (const float*)d_in[12];
    float* out = (float*)d_out;
    float* ws  = (float*)d_ws;

    float* sums0 = ws;             // 4096
    float* mu1   = ws + 4096;      // 4096
    float* rs1   = ws + 8192;      // 4096
    float* sumxs = ws + 12288;     // 4096
    float* s0    = ws + 16384;     // 4096
    float* gd1   = ws + 20480;     // 4096

    pass1_kernel<<<NPLANES, 256, 0, stream>>>(x, gnw, gnb, sw, sb,
                                              sums0, mu1, rs1, sumxs);
    gates_kernel<<<NS, 64, 0, stream>>>(sums0, mu1, sumxs, cw, cb,
                                        fc1w, fc1b, lnw, lnb, fc2w, fc2b,
                                        s0, gd1);
    out_kernel<<<NPLANES, 256, 0, stream>>>(x, out, s0, mu1, rs1,
                                            gnw, gnb, sw, sb, gd1);
}

// Round 3
// 67.770 us; speedup vs baseline: 1.2183x; 1.0209x over previous
//
#include <hip/hip_runtime.h>
#include <math.h>

#define HW 4096      // 64*64
#define CS 32        // channels per branch
#define NS 128       // B*GROUPS samples
#define NPLANES 8192 // NS * 64
#define EPS 1e-5f

typedef float vfloat4 __attribute__((ext_vector_type(4)));

__device__ __forceinline__ float sigmoidf_(float x) {
    return 1.0f / (1.0f + __expf(-x));
}

__device__ __forceinline__ void nt_store4(float4* p, float4 v) {
    __builtin_nontemporal_store(*(const vfloat4*)&v, (vfloat4*)p);
}

// block-wide (256 thr, 4 waves) sum reduce; result valid in all threads
__device__ __forceinline__ float block_reduce(float s, float* ls, int tid) {
    for (int off = 32; off > 0; off >>= 1) s += __shfl_down(s, off, 64);
    const int wave = tid >> 6, lane = tid & 63;
    if (lane == 0) ls[wave] = s;
    __syncthreads();
    return ls[0] + ls[1] + ls[2] + ls[3];
}

// ---------------- K1: one read of x.
// branch0 plane -> channel sum; branch1 plane -> mu, rs, sum(xs) (reg-staged)
__global__ __launch_bounds__(256) void pass1_kernel(
    const float* __restrict__ x,
    const float* __restrict__ gnw, const float* __restrict__ gnb,
    const float* __restrict__ sw,  const float* __restrict__ sb,
    float* __restrict__ sums0, float* __restrict__ mu1,
    float* __restrict__ rs1,   float* __restrict__ sumxs) {
    const int P = blockIdx.x;
    const int n = P >> 6, cc = P & 63;
    const int tid = threadIdx.x;
    const float4* xp = (const float4*)(x + (size_t)P * HW);
    __shared__ float ls[4];
    __shared__ float bc[2];

    if (cc < CS) {
        float s = 0.f;
#pragma unroll
        for (int k = 0; k < 4; ++k) {
            float4 v = xp[tid + k * 256];
            s += v.x + v.y + v.z + v.w;
        }
        s = block_reduce(s, ls, tid);
        if (tid == 0) sums0[n * CS + cc] = s;
    } else {
        const int c = cc - CS;
        float4 v[4];
        float s = 0.f, s2 = 0.f;
#pragma unroll
        for (int k = 0; k < 4; ++k) {
            v[k] = xp[tid + k * 256];
            s  += v[k].x + v[k].y + v[k].z + v[k].w;
            s2 += v[k].x * v[k].x + v[k].y * v[k].y
                + v[k].z * v[k].z + v[k].w * v[k].w;
        }
        for (int off = 32; off > 0; off >>= 1) {
            s  += __shfl_down(s, off, 64);
            s2 += __shfl_down(s2, off, 64);
        }
        __shared__ float ls2[4];
        const int wave = tid >> 6, lane = tid & 63;
        if (lane == 0) { ls[wave] = s; ls2[wave] = s2; }
        __syncthreads();
        if (tid == 0) {
            float st  = ls[0] + ls[1] + ls[2] + ls[3];
            float s2t = ls2[0] + ls2[1] + ls2[2] + ls2[3];
            float mu  = st * (1.0f / HW);
            float var = s2t * (1.0f / HW) - mu * mu;
            float rs  = rsqrtf(var + EPS);
            mu1[n * CS + c] = mu;
            rs1[n * CS + c] = rs;
            bc[0] = mu; bc[1] = rs;
        }
        __syncthreads();
        const float mu = bc[0], rs = bc[1];
        const float a  = gnw[c] * rs;
        const float b0 = gnb[c] - mu * a;
        const float sbv = sb[c];
        const float4* wp = (const float4*)(sw + (size_t)c * HW);
        float sx = 0.f;
#pragma unroll
        for (int k = 0; k < 4; ++k) {
            float4 w = wp[tid + k * 256];
            sx += v[k].x * sigmoidf_(w.x * (v[k].x * a + b0) + sbv);
            sx += v[k].y * sigmoidf_(w.y * (v[k].y * a + b0) + sbv);
            sx += v[k].z * sigmoidf_(w.z * (v[k].z * a + b0) + sbv);
            sx += v[k].w * sigmoidf_(w.w * (v[k].w * a + b0) + sbv);
        }
        __syncthreads();   // ls reuse
        sx = block_reduce(sx, ls, tid);
        if (tid == 0) sumxs[n * CS + c] = sx;
    }
}

// ---------------- K2: fused gates + output pass (both branches)
__global__ __launch_bounds__(256) void out_kernel(
    const float* __restrict__ x, float* __restrict__ out,
    const float* __restrict__ sums0,
    const float* __restrict__ mu1, const float* __restrict__ rs1,
    const float* __restrict__ sumxs,
    const float* __restrict__ cw,  const float* __restrict__ cb,
    const float* __restrict__ gnw, const float* __restrict__ gnb,
    const float* __restrict__ sw,  const float* __restrict__ sb,
    const float* __restrict__ fc1w, const float* __restrict__ fc1b,
    const float* __restrict__ lnw, const float* __restrict__ lnb,
    const float* __restrict__ fc2w, const float* __restrict__ fc2b) {
    const int P = blockIdx.x;
    const int n = P >> 6, cc = P & 63;
    const int tid = threadIdx.x;
    const int branch = (cc >= CS);
    const int c0 = cc & 31;

    __shared__ float pS[CS], qS[CS], rS[CS], g0S[CS];
    __shared__ float scaleS;

    // ---- redundant per-block gate MLP (threads of wave 0) ----
    if (tid < CS) {
        float pv;
        if (!branch) {
            float mean = sums0[n * CS + tid] * (1.0f / HW);
            float g0 = sigmoidf_(cw[tid] * mean + cb[tid]);
            g0S[tid] = g0;
            pv = mean * (1.0f - g0);          // mean of x_reid_0
        } else {
            pv = mu1[n * CS + tid] - sumxs[n * CS + tid] * (1.0f / HW);
        }
        pS[tid] = pv;
    }
    __syncthreads();
    if (tid < CS) {
        float qv = fc1b[tid];
        for (int j = 0; j < CS; ++j) qv += fc1w[tid * CS + j] * pS[j];
        qS[tid] = qv;
    }
    __syncthreads();
    if (tid < CS) {
        float mu = 0.f;
        for (int j = 0; j < CS; ++j) mu += qS[j];
        mu *= (1.0f / CS);
        float var = 0.f;
        for (int j = 0; j < CS; ++j) { float d = qS[j] - mu; var += d * d; }
        var *= (1.0f / CS);
        float qn = (qS[tid] - mu) * rsqrtf(var + EPS) * lnw[tid] + lnb[tid];
        rS[tid] = fmaxf(qn, 0.f);
    }
    __syncthreads();
    if (tid < 64) {   // whole wave 0 active -> well-defined shuffles
        float t = (tid < CS) ? fc2w[c0 * CS + tid] * rS[tid] : 0.f;
        for (int off = 32; off > 0; off >>= 1) t += __shfl_down(t, off, 64);
        if (tid == 0) {
            float gd = sigmoidf_(t + fc2b[c0]);
            scaleS = branch ? gd : (g0S[c0] + (1.0f - g0S[c0]) * gd);
        }
    }
    __syncthreads();

    const float4* xp = (const float4*)(x + (size_t)P * HW);
    float4* op = (float4*)(out + (size_t)P * HW);

    if (!branch) {
        const float scale = scaleS;
#pragma unroll
        for (int k = 0; k < 4; ++k) {
            float4 v = xp[tid + k * 256];
            v.x *= scale; v.y *= scale; v.z *= scale; v.w *= scale;
            nt_store4(op + tid + k * 256, v);
        }
    } else {
        const float g  = scaleS;
        const float mu = mu1[n * CS + c0], rs = rs1[n * CS + c0];
        const float a  = gnw[c0] * rs;
        const float b0 = gnb[c0] - mu * a;
        const float sbv = sb[c0];
        const float4* wp = (const float4*)(sw + (size_t)c0 * HW);
#pragma unroll
        for (int k = 0; k < 4; ++k) {
            float4 v = xp[tid + k * 256];
            float4 w = wp[tid + k * 256];
            float4 o; float sg;
            sg = sigmoidf_(w.x * (v.x * a + b0) + sbv); o.x = v.x * (sg + (1.f - sg) * g);
            sg = sigmoidf_(w.y * (v.y * a + b0) + sbv); o.y = v.y * (sg + (1.f - sg) * g);
            sg = sigmoidf_(w.z * (v.z * a + b0) + sbv); o.z = v.z * (sg + (1.f - sg) * g);
            sg = sigmoidf_(w.w * (v.w * a + b0) + sbv); o.w = v.w * (sg + (1.f - sg) * g);
            nt_store4(op + tid + k * 256, o);
        }
    }
}

extern "C" void kernel_launch(void* const* d_in, const int* in_sizes, int n_in,
                              void* d_out, int out_size, void* d_ws, size_t ws_size,
                              hipStream_t stream) {
    const float* x    = (const float*)d_in[0];
    const float* cw   = (const float*)d_in[1];
    const float* cb   = (const float*)d_in[2];
    const float* sw   = (const float*)d_in[3];
    const float* sb   = (const float*)d_in[4];
    const float* gnw  = (const float*)d_in[5];
    const float* gnb  = (const float*)d_in[6];
    const float* fc1w = (const float*)d_in[7];
    const float* fc1b = (const float*)d_in[8];
    const float* lnw  = (const float*)d_in[9];
    const float* lnb  = (const float*)d_in[10];
    const float* fc2w = (const float*)d_in[11];
    const float* fc2b = (const float*)d_in[12];
    float* out = (float*)d_out;
    float* ws  = (float*)d_ws;

    float* sums0 = ws;             // 4096
    float* mu1   = ws + 4096;      // 4096
    float* rs1   = ws + 8192;      // 4096
    float* sumxs = ws + 12288;     // 4096

    pass1_kernel<<<NPLANES, 256, 0, stream>>>(x, gnw, gnb, sw, sb,
                                              sums0, mu1, rs1, sumxs);
    out_kernel<<<NPLANES, 256, 0, stream>>>(x, out, sums0, mu1, rs1, sumxs,
                                            cw, cb, gnw, gnb, sw, sb,
                                            fc1w, fc1b, lnw, lnb, fc2w, fc2b);
}